// Round 6
// baseline (650.430 us; speedup 1.0000x reference)
//
#include <hip/hip_runtime.h>
#include <stdint.h>

typedef __attribute__((ext_vector_type(8))) short short8;
typedef __attribute__((ext_vector_type(16))) float floatx16;
typedef __attribute__((ext_vector_type(2))) short s16x2;
typedef unsigned int u32;
typedef unsigned short u16;

#define TPW 6        // tiles (of 32 points) per wave; processed 2 at a time
#define WPB 8        // waves per block (512 threads)

#if defined(__has_builtin)
#if __has_builtin(__builtin_elementwise_max)
#define HAVE_PK_MAX 1
#endif
#endif

// f32 pair -> packed bf16 (a->low16, b->high16), round-half-up.
// Same 0.5-ulp error bound as RNE (differs only on exact ties); 3 VALU ops.
__device__ __forceinline__ u32 pkhu(float a, float b) {
  return __builtin_amdgcn_perm(__float_as_uint(b) + 0x8000u,
                               __float_as_uint(a) + 0x8000u, 0x07060302u);
}

// relu on a packed bf16 pair: signed-i16 max with 0 (sign bit => clamp to +0).
__device__ __forceinline__ u32 relu_pk(u32 t) {
#ifdef HAVE_PK_MAX
  union { u32 u; s16x2 v; } c;
  c.u = t;
  s16x2 zz = {0, 0};
  c.v = __builtin_elementwise_max(c.v, zz);  // v_pk_max_i16
  return c.u;
#else
  return t;  // unused in fallback path
#endif
}

// RNE f32->bf16 (prologue weights only — bit-identical to R3/R4/R5 weights)
__device__ __forceinline__ u16 rtn1(float a) {
  u32 ua = __float_as_uint(a);
  ua += 0x7fffu + ((ua >> 16) & 1u);
  return (u16)(ua >> 16);
}

// channel<->k-slot permutation (involution): swap bits 2 and 3 of low nibble.
// (Algebra HW-verified: R1/R3/R4/R5 passed, absmax 4.8e-3.)
__device__ __forceinline__ int sigperm(int k) {
  int r = k & 15;
  int s = (r & 3) | ((r & 4) << 1) | ((r & 8) >> 1);
  return (k & ~15) | s;
}

// pack 8 consecutive accumulator regs (base=0 or 8) into one B-frag
__device__ __forceinline__ short8 packhalf(const floatx16 a, int base, bool relu) {
  union { u32 u[4]; short8 v; } r;
#pragma unroll
  for (int i = 0; i < 4; ++i) {
    float p = a[base + 2 * i];
    float q = a[base + 2 * i + 1];
#ifdef HAVE_PK_MAX
    u32 t = pkhu(p, q);
    if (relu) t = relu_pk(t);
    r.u[i] = t;
#else
    if (relu) { p = fmaxf(p, 0.0f); q = fmaxf(q, 0.0f); }
    r.u[i] = pkhu(p, q);
#endif
  }
  return r.v;
}

#define MFMA(A, B, C) __builtin_amdgcn_mfma_f32_32x32x16_bf16(A, B, C, 0, 0, 0)

// Frag-major LDS: 38 frags x 64 lanes x 16B. Frag ids:
//  0..1  s0[rt]          2..9  s1[rt*4+ks]    10..13 s2[ks]
// 14..17 c0[rt*2+ks]    18..25 c1[rt*4+ks]    26..33 c2[rt*4+ks]   34..37 c3[ks]
#define NFRAG 38

__global__ __launch_bounds__(512, 7) void nerf_fused(
    const float* __restrict__ x,
    const float* __restrict__ w_s0, const float* __restrict__ w_s1,
    const float* __restrict__ w_s2, const float* __restrict__ w_c0,
    const float* __restrict__ w_c1, const float* __restrict__ w_c2,
    const float* __restrict__ w_c3,
    float* __restrict__ out, int npts) {
  __shared__ __align__(16) u16 wl[NFRAG * 512];  // 38912 B -> 3 blocks/CU

  const int lane = threadIdx.x & 63;
  const int wid = threadIdx.x >> 6;  // 0..7
  const int m = lane & 31;   // A-row / B-col (point) index within tile
  const int hi = lane >> 5;  // half-wave -> k-block
  const int kb = hi << 3;

  // ---- prologue: build fragments straight from global, store frag-major ----
  for (int f = wid; f < NFRAG; f += WPB) {
    union { u16 e[8]; uint4 q; } u;
    if (f < 2) {                         // s0: 64x3, K padded to 16
      const int row = f * 32 + m;
#pragma unroll
      for (int j = 0; j < 8; ++j) {
        const int k = kb + j;
        u.e[j] = (k < 3) ? rtn1(w_s0[row * 3 + k]) : (u16)0;
      }
    } else if (f < 10) {                 // s1: 64x64
      const int g = f - 2, rt = g >> 2, ks = g & 3;
      const int row = rt * 32 + m;
#pragma unroll
      for (int j = 0; j < 8; ++j)
        u.e[j] = rtn1(w_s1[row * 64 + sigperm(ks * 16 + kb + j)]);
    } else if (f < 14) {                 // s2: 16x64 (rows 16..31 zero)
      const int ks = f - 10;
      const int row = (m < 16) ? m : 0;
#pragma unroll
      for (int j = 0; j < 8; ++j) {
        u16 v = rtn1(w_s2[row * 64 + sigperm(ks * 16 + kb + j)]);
        u.e[j] = (m < 16) ? v : (u16)0;
      }
    } else if (f < 18) {                 // c0: 64x18 (geo slots + view slots)
      const int g = f - 14, rt = g >> 1, ks = g & 1;
      const int row = rt * 32 + m;
#pragma unroll
      for (int j = 0; j < 8; ++j) {
        if (ks == 0) {
          const int c = sigperm(kb + j);   // s2-output channel in this k-slot
          u16 v = rtn1(w_c0[row * 18 + (c + 2)]);
          u.e[j] = (c == 0) ? (u16)0 : v;  // ch0 = sigma -> weight 0
        } else {
          const int kk = kb + j;           // views at k=0..2 of 2nd MFMA
          u16 v = rtn1(w_c0[row * 18 + kk]);
          u.e[j] = (kk < 3) ? v : (u16)0;
        }
      }
    } else if (f < 26) {                 // c1: 64x64
      const int g = f - 18, rt = g >> 2, ks = g & 3;
      const int row = rt * 32 + m;
#pragma unroll
      for (int j = 0; j < 8; ++j)
        u.e[j] = rtn1(w_c1[row * 64 + sigperm(ks * 16 + kb + j)]);
    } else if (f < 34) {                 // c2: 64x64
      const int g = f - 26, rt = g >> 2, ks = g & 3;
      const int row = rt * 32 + m;
#pragma unroll
      for (int j = 0; j < 8; ++j)
        u.e[j] = rtn1(w_c2[row * 64 + sigperm(ks * 16 + kb + j)]);
    } else {                             // c3: 3x64 (rows 3..31 zero)
      const int ks = f - 34;
      const int row = (m < 3) ? m : 0;
#pragma unroll
      for (int j = 0; j < 8; ++j) {
        u16 v = rtn1(w_c3[row * 64 + sigperm(ks * 16 + kb + j)]);
        u.e[j] = (m < 3) ? v : (u16)0;
      }
    }
    *(uint4*)(wl + f * 512 + lane * 8) = u.q;
  }
  __syncthreads();

#define LD(F) (*(const short8*)(wl + (F) * 512 + lane * 8))

  // ---- main loop: 2 independent tiles (64 points) per iteration ----
  const int ntiles = npts >> 5;
  const int wgid = blockIdx.x * WPB + wid;
  const floatx16 z = (floatx16)0.0f;

  for (int t = 0; t < TPW; t += 2) {
    const int tileA = wgid * TPW + t;
    if (tileA >= ntiles) break;
    const int ptA = (tileA << 5) | m;
    const int ptB = ptA + 32;  // tileA is even & ntiles even -> tileB valid

    const float2* xpA = (const float2*)(x + (size_t)ptA * 6);
    const float2 a0 = xpA[0], a1 = xpA[1], a2 = xpA[2];
    const float2* xpB = (const float2*)(x + (size_t)ptB * 6);
    const float2 c0_ = xpB[0], c1_ = xpB[1], c2_ = xpB[2];

    union { u32 u[4]; short8 v; } bxA, bvA, bxB, bvB;
    bxA.u[0] = hi ? 0u : pkhu(a0.x, a0.y);
    bxA.u[1] = hi ? 0u : pkhu(a1.x, 0.0f);
    bxA.u[2] = 0u; bxA.u[3] = 0u;
    bvA.u[0] = hi ? 0u : pkhu(a1.y, a2.x);
    bvA.u[1] = hi ? 0u : pkhu(a2.y, 0.0f);
    bvA.u[2] = 0u; bvA.u[3] = 0u;
    bxB.u[0] = hi ? 0u : pkhu(c0_.x, c0_.y);
    bxB.u[1] = hi ? 0u : pkhu(c1_.x, 0.0f);
    bxB.u[2] = 0u; bxB.u[3] = 0u;
    bvB.u[0] = hi ? 0u : pkhu(c1_.y, c2_.x);
    bvB.u[1] = hi ? 0u : pkhu(c2_.y, 0.0f);
    bvB.u[2] = 0u; bvB.u[3] = 0u;

    floatx16 hA0, hA1, hB0, hB1;
    short8 w;

    // sigma L0 (K=3 padded)
    w = LD(0); hA0 = MFMA(w, bxA.v, z); hB0 = MFMA(w, bxB.v, z);
    w = LD(1); hA1 = MFMA(w, bxA.v, z); hB1 = MFMA(w, bxB.v, z);
    short8 bA0 = packhalf(hA0, 0, true), bA1 = packhalf(hA0, 8, true);
    short8 bA2 = packhalf(hA1, 0, true), bA3 = packhalf(hA1, 8, true);
    short8 bB0 = packhalf(hB0, 0, true), bB1 = packhalf(hB0, 8, true);
    short8 bB2 = packhalf(hB1, 0, true), bB3 = packhalf(hB1, 8, true);

    // sigma L1 (64->64)
    w = LD(2); hA0 = MFMA(w, bA0, z);   hB0 = MFMA(w, bB0, z);
    w = LD(6); hA1 = MFMA(w, bA0, z);   hB1 = MFMA(w, bB0, z);
    w = LD(3); hA0 = MFMA(w, bA1, hA0); hB0 = MFMA(w, bB1, hB0);
    w = LD(7); hA1 = MFMA(w, bA1, hA1); hB1 = MFMA(w, bB1, hB1);
    w = LD(4); hA0 = MFMA(w, bA2, hA0); hB0 = MFMA(w, bB2, hB0);
    w = LD(8); hA1 = MFMA(w, bA2, hA1); hB1 = MFMA(w, bB2, hB1);
    w = LD(5); hA0 = MFMA(w, bA3, hA0); hB0 = MFMA(w, bB3, hB0);
    w = LD(9); hA1 = MFMA(w, bA3, hA1); hB1 = MFMA(w, bB3, hB1);
    bA0 = packhalf(hA0, 0, true); bA1 = packhalf(hA0, 8, true);
    bA2 = packhalf(hA1, 0, true); bA3 = packhalf(hA1, 8, true);
    bB0 = packhalf(hB0, 0, true); bB1 = packhalf(hB0, 8, true);
    bB2 = packhalf(hB1, 0, true); bB3 = packhalf(hB1, 8, true);

    // sigma L2 (64->16, NO relu)
    floatx16 hsA, hsB;
    w = LD(10); hsA = MFMA(w, bA0, z);   hsB = MFMA(w, bB0, z);
    w = LD(11); hsA = MFMA(w, bA1, hsA); hsB = MFMA(w, bB1, hsB);
    w = LD(12); hsA = MFMA(w, bA2, hsA); hsB = MFMA(w, bB2, hsB);
    w = LD(13); hsA = MFMA(w, bA3, hsA); hsB = MFMA(w, bB3, hsB);
    const float sigmaA = hsA[0], sigmaB = hsB[0];
    const short8 bs2A = packhalf(hsA, 0, false);
    const short8 bs2B = packhalf(hsB, 0, false);

    // color L0 (19->64: s2 slots + views)
    w = LD(14); hA0 = MFMA(w, bs2A, z);    hB0 = MFMA(w, bs2B, z);
    w = LD(16); hA1 = MFMA(w, bs2A, z);    hB1 = MFMA(w, bs2B, z);
    w = LD(15); hA0 = MFMA(w, bvA.v, hA0); hB0 = MFMA(w, bvB.v, hB0);
    w = LD(17); hA1 = MFMA(w, bvA.v, hA1); hB1 = MFMA(w, bvB.v, hB1);
    bA0 = packhalf(hA0, 0, true); bA1 = packhalf(hA0, 8, true);
    bA2 = packhalf(hA1, 0, true); bA3 = packhalf(hA1, 8, true);
    bB0 = packhalf(hB0, 0, true); bB1 = packhalf(hB0, 8, true);
    bB2 = packhalf(hB1, 0, true); bB3 = packhalf(hB1, 8, true);

    // color L1
    w = LD(18); hA0 = MFMA(w, bA0, z);   hB0 = MFMA(w, bB0, z);
    w = LD(22); hA1 = MFMA(w, bA0, z);   hB1 = MFMA(w, bB0, z);
    w = LD(19); hA0 = MFMA(w, bA1, hA0); hB0 = MFMA(w, bB1, hB0);
    w = LD(23); hA1 = MFMA(w, bA1, hA1); hB1 = MFMA(w, bB1, hB1);
    w = LD(20); hA0 = MFMA(w, bA2, hA0); hB0 = MFMA(w, bB2, hB0);
    w = LD(24); hA1 = MFMA(w, bA2, hA1); hB1 = MFMA(w, bB2, hB1);
    w = LD(21); hA0 = MFMA(w, bA3, hA0); hB0 = MFMA(w, bB3, hB0);
    w = LD(25); hA1 = MFMA(w, bA3, hA1); hB1 = MFMA(w, bB3, hB1);
    bA0 = packhalf(hA0, 0, true); bA1 = packhalf(hA0, 8, true);
    bA2 = packhalf(hA1, 0, true); bA3 = packhalf(hA1, 8, true);
    bB0 = packhalf(hB0, 0, true); bB1 = packhalf(hB0, 8, true);
    bB2 = packhalf(hB1, 0, true); bB3 = packhalf(hB1, 8, true);

    // color L2
    w = LD(26); hA0 = MFMA(w, bA0, z);   hB0 = MFMA(w, bB0, z);
    w = LD(30); hA1 = MFMA(w, bA0, z);   hB1 = MFMA(w, bB0, z);
    w = LD(27); hA0 = MFMA(w, bA1, hA0); hB0 = MFMA(w, bB1, hB0);
    w = LD(31); hA1 = MFMA(w, bA1, hA1); hB1 = MFMA(w, bB1, hB1);
    w = LD(28); hA0 = MFMA(w, bA2, hA0); hB0 = MFMA(w, bB2, hB0);
    w = LD(32); hA1 = MFMA(w, bA2, hA1); hB1 = MFMA(w, bB2, hB1);
    w = LD(29); hA0 = MFMA(w, bA3, hA0); hB0 = MFMA(w, bB3, hB0);
    w = LD(33); hA1 = MFMA(w, bA3, hA1); hB1 = MFMA(w, bB3, hB1);
    bA0 = packhalf(hA0, 0, true); bA1 = packhalf(hA0, 8, true);
    bA2 = packhalf(hA1, 0, true); bA3 = packhalf(hA1, 8, true);
    bB0 = packhalf(hB0, 0, true); bB1 = packhalf(hB0, 8, true);
    bB2 = packhalf(hB1, 0, true); bB3 = packhalf(hB1, 8, true);

    // color L3 (64->3, NO relu)
    floatx16 hcA, hcB;
    w = LD(34); hcA = MFMA(w, bA0, z);   hcB = MFMA(w, bB0, z);
    w = LD(35); hcA = MFMA(w, bA1, hcA); hcB = MFMA(w, bB1, hcB);
    w = LD(36); hcA = MFMA(w, bA2, hcA); hcB = MFMA(w, bB2, hcB);
    w = LD(37); hcA = MFMA(w, bA3, hcA); hcB = MFMA(w, bB3, hcB);

    if (lane < 32) {
      float4 oA, oB;
      oA.x = hcA[0]; oA.y = hcA[1]; oA.z = hcA[2]; oA.w = sigmaA;
      oB.x = hcB[0]; oB.y = hcB[1]; oB.z = hcB[2]; oB.w = sigmaB;
      *(float4*)(out + (size_t)ptA * 4) = oA;
      *(float4*)(out + (size_t)ptB * 4) = oB;
    }
  }
#undef LD
}

extern "C" void kernel_launch(void* const* d_in, const int* in_sizes, int n_in,
                              void* d_out, int out_size, void* d_ws, size_t ws_size,
                              hipStream_t stream) {
  const float* x = (const float*)d_in[0];
  const float* sw0 = (const float*)d_in[1];
  const float* sw1 = (const float*)d_in[2];
  const float* sw2 = (const float*)d_in[3];
  const float* cw0 = (const float*)d_in[4];
  const float* cw1 = (const float*)d_in[5];
  const float* cw2 = (const float*)d_in[6];
  const float* cw3 = (const float*)d_in[7];
  float* out = (float*)d_out;

  const int npts = in_sizes[0] / 6;         // 1048576
  const int ntiles = npts >> 5;             // 32768
  int blocks = (ntiles + WPB * TPW - 1) / (WPB * TPW);  // 683 for 1M pts
  if (blocks < 768) blocks = 768;           // 3 blocks/CU, all co-resident

  nerf_fused<<<blocks, WPB * 64, 0, stream>>>(x, sw0, sw1, sw2, cw0, cw1, cw2,
                                              cw3, out, npts);
}

// Round 10
// 116.706 us; speedup vs baseline: 5.5732x; 5.5732x over previous
//
#include <hip/hip_runtime.h>
#include <stdint.h>

typedef __attribute__((ext_vector_type(8))) _Float16 half8;
typedef __attribute__((ext_vector_type(2))) __fp16 fp16x2;
typedef __attribute__((ext_vector_type(16))) float floatx16;
typedef __attribute__((ext_vector_type(2))) short s16x2;
typedef unsigned int u32;
typedef unsigned short u16;

#define TPW 8  // tiles (of 32 points) per wave; processed 2 at a time

// f32 pair -> packed f16 (a->low16, b->high16), single v_cvt_pkrtz_f16_f32.
// Builtin returns __fp16-vector (NOT _Float16-vector) — union must match.
// NOTE R7: v_cvt_pk_bf16_f32 asm assembles on gfx950 but returns garbage.
// NOTE R8: inline-asm v_mfma_* corrupts results (no hazard nops) — never
// hand-emit MFMA via asm; intrinsics only.
__device__ __forceinline__ u32 pkf16(float a, float b) {
  union { fp16x2 v; u32 u; } c;
  c.v = __builtin_amdgcn_cvt_pkrtz(a, b);
  return c.u;
}

// relu on a packed 16-bit-float pair: signed-i16 max with 0 (sign bit =>
// negative as i16 => clamped to +0; positives ordered). R5-proven.
__device__ __forceinline__ u32 relu_pk(u32 t) {
  union { u32 u; s16x2 v; } c;
  c.u = t;
  s16x2 zz = {0, 0};
  c.v = __builtin_elementwise_max(c.v, zz);  // v_pk_max_i16
  return c.u;
}

// RNE f32->f16 for prologue weights
__device__ __forceinline__ u16 rtnh(float a) {
  union { _Float16 h; u16 u; } c;
  c.h = (_Float16)a;  // v_cvt_f16_f32 (RNE)
  return c.u;
}

// channel<->k-slot permutation (involution): swap bits 2 and 3 of low nibble.
// Maps C/D register order onto B-operand k-slots; baked into weight gather.
// Dtype-independent (C/D layout is shape-determined; verified bf16 R1-R5).
__device__ __forceinline__ int sigperm(int k) {
  int r = k & 15;
  int s = (r & 3) | ((r & 4) << 1) | ((r & 8) >> 1);
  return (k & ~15) | s;
}

// pack 8 consecutive accumulator regs (base=0 or 8) into one B-frag
__device__ __forceinline__ half8 packhalf(const floatx16 a, int base, bool relu) {
  union { u32 u[4]; half8 v; } r;
#pragma unroll
  for (int i = 0; i < 4; ++i) {
    u32 t = pkf16(a[base + 2 * i], a[base + 2 * i + 1]);
    r.u[i] = relu ? relu_pk(t) : t;
  }
  return r.v;
}

#define MFMA(A, B, C) __builtin_amdgcn_mfma_f32_32x32x16_f16(A, B, C, 0, 0, 0)

// Frag-major LDS: 38 frags x 64 lanes x 16B. Frag ids:
//  0..1  s0[rt]          2..9  s1[rt*4+ks]    10..13 s2[ks]
// 14..17 c0[rt*2+ks]    18..25 c1[rt*4+ks]    26..33 c2[rt*4+ks]   34..37 c3[ks]
#define NFRAG 38

// NOTE: live set ~132 unified regs (68 arch + 64 MFMA acc). (256,3) is the
// max safe launch bound; (512,7) spilled catastrophically in R6 (650 us).
__global__ __launch_bounds__(256, 3) void nerf_fused(
    const float* __restrict__ x,
    const float* __restrict__ w_s0, const float* __restrict__ w_s1,
    const float* __restrict__ w_s2, const float* __restrict__ w_c0,
    const float* __restrict__ w_c1, const float* __restrict__ w_c2,
    const float* __restrict__ w_c3,
    float* __restrict__ out, int npts) {
  __shared__ __align__(16) u16 wl[NFRAG * 512];  // 38912 B

  const int lane = threadIdx.x & 63;
  const int wid = threadIdx.x >> 6;
  const int m = lane & 31;   // A-row / B-col (point) index within tile
  const int hi = lane >> 5;  // half-wave -> k-block
  const int kb = hi << 3;

  // ---- prologue: build fragments straight from global, store frag-major ----
  for (int f = wid; f < NFRAG; f += 4) {
    union { u16 e[8]; uint4 q; } u;
    if (f < 2) {                         // s0: 64x3, K padded to 16
      const int row = f * 32 + m;
#pragma unroll
      for (int j = 0; j < 8; ++j) {
        const int k = kb + j;
        u.e[j] = (k < 3) ? rtnh(w_s0[row * 3 + k]) : (u16)0;
      }
    } else if (f < 10) {                 // s1: 64x64
      const int g = f - 2, rt = g >> 2, ks = g & 3;
      const int row = rt * 32 + m;
#pragma unroll
      for (int j = 0; j < 8; ++j)
        u.e[j] = rtnh(w_s1[row * 64 + sigperm(ks * 16 + kb + j)]);
    } else if (f < 14) {                 // s2: 16x64 (rows 16..31 zero)
      const int ks = f - 10;
      const int row = (m < 16) ? m : 0;
#pragma unroll
      for (int j = 0; j < 8; ++j) {
        u16 v = rtnh(w_s2[row * 64 + sigperm(ks * 16 + kb + j)]);
        u.e[j] = (m < 16) ? v : (u16)0;
      }
    } else if (f < 18) {                 // c0: 64x18 (geo slots + view slots)
      const int g = f - 14, rt = g >> 1, ks = g & 1;
      const int row = rt * 32 + m;
#pragma unroll
      for (int j = 0; j < 8; ++j) {
        if (ks == 0) {
          const int c = sigperm(kb + j);   // s2-output channel in this k-slot
          u16 v = rtnh(w_c0[row * 18 + (c + 2)]);
          u.e[j] = (c == 0) ? (u16)0 : v;  // ch0 = sigma -> weight 0
        } else {
          const int kk = kb + j;           // views at k=0..2 of 2nd MFMA
          u16 v = rtnh(w_c0[row * 18 + kk]);
          u.e[j] = (kk < 3) ? v : (u16)0;
        }
      }
    } else if (f < 26) {                 // c1: 64x64
      const int g = f - 18, rt = g >> 2, ks = g & 3;
      const int row = rt * 32 + m;
#pragma unroll
      for (int j = 0; j < 8; ++j)
        u.e[j] = rtnh(w_c1[row * 64 + sigperm(ks * 16 + kb + j)]);
    } else if (f < 34) {                 // c2: 64x64
      const int g = f - 26, rt = g >> 2, ks = g & 3;
      const int row = rt * 32 + m;
#pragma unroll
      for (int j = 0; j < 8; ++j)
        u.e[j] = rtnh(w_c2[row * 64 + sigperm(ks * 16 + kb + j)]);
    } else {                             // c3: 3x64 (rows 3..31 zero)
      const int ks = f - 34;
      const int row = (m < 3) ? m : 0;
#pragma unroll
      for (int j = 0; j < 8; ++j) {
        u16 v = rtnh(w_c3[row * 64 + sigperm(ks * 16 + kb + j)]);
        u.e[j] = (m < 3) ? v : (u16)0;
      }
    }
    *(uint4*)(wl + f * 512 + lane * 8) = u.q;
  }
  __syncthreads();

#define LD(F) (*(const half8*)(wl + (F) * 512 + lane * 8))

  // ---- main loop: 2 independent tiles (64 points) per iteration ----
  const int ntiles = npts >> 5;
  const int wgid = blockIdx.x * 4 + wid;
  const floatx16 z = (floatx16)0.0f;

  for (int t = 0; t < TPW; t += 2) {
    const int tileA = wgid * TPW + t;
    if (tileA >= ntiles) break;
    const int ptA = (tileA << 5) | m;
    const int ptB = ptA + 32;  // tileA is even & ntiles even -> tileB valid

    const float2* xpA = (const float2*)(x + (size_t)ptA * 6);
    const float2 a0 = xpA[0], a1 = xpA[1], a2 = xpA[2];
    const float2* xpB = (const float2*)(x + (size_t)ptB * 6);
    const float2 c0_ = xpB[0], c1_ = xpB[1], c2_ = xpB[2];

    union { u32 u[4]; half8 v; } bxA, bvA, bxB, bvB;
    bxA.u[0] = hi ? 0u : pkf16(a0.x, a0.y);   // (p0,p1) at k0,k1
    bxA.u[1] = hi ? 0u : pkf16(a1.x, 0.0f);   // (p2, 0)
    bxA.u[2] = 0u; bxA.u[3] = 0u;
    bvA.u[0] = hi ? 0u : pkf16(a1.y, a2.x);   // (v0,v1)
    bvA.u[1] = hi ? 0u : pkf16(a2.y, 0.0f);   // (v2, 0)
    bvA.u[2] = 0u; bvA.u[3] = 0u;
    bxB.u[0] = hi ? 0u : pkf16(c0_.x, c0_.y);
    bxB.u[1] = hi ? 0u : pkf16(c1_.x, 0.0f);
    bxB.u[2] = 0u; bxB.u[3] = 0u;
    bvB.u[0] = hi ? 0u : pkf16(c1_.y, c2_.x);
    bvB.u[1] = hi ? 0u : pkf16(c2_.y, 0.0f);
    bvB.u[2] = 0u; bvB.u[3] = 0u;

    floatx16 hA0, hA1, hB0, hB1;
    half8 w;

    // sigma L0 (K=3 padded)
    w = LD(0); hA0 = MFMA(w, bxA.v, z); hB0 = MFMA(w, bxB.v, z);
    w = LD(1); hA1 = MFMA(w, bxA.v, z); hB1 = MFMA(w, bxB.v, z);
    half8 bA0 = packhalf(hA0, 0, true), bA1 = packhalf(hA0, 8, true);
    half8 bA2 = packhalf(hA1, 0, true), bA3 = packhalf(hA1, 8, true);
    half8 bB0 = packhalf(hB0, 0, true), bB1 = packhalf(hB0, 8, true);
    half8 bB2 = packhalf(hB1, 0, true), bB3 = packhalf(hB1, 8, true);

    // sigma L1 (64->64)
    w = LD(2); hA0 = MFMA(w, bA0, z);   hB0 = MFMA(w, bB0, z);
    w = LD(6); hA1 = MFMA(w, bA0, z);   hB1 = MFMA(w, bB0, z);
    w = LD(3); hA0 = MFMA(w, bA1, hA0); hB0 = MFMA(w, bB1, hB0);
    w = LD(7); hA1 = MFMA(w, bA1, hA1); hB1 = MFMA(w, bB1, hB1);
    w = LD(4); hA0 = MFMA(w, bA2, hA0); hB0 = MFMA(w, bB2, hB0);
    w = LD(8); hA1 = MFMA(w, bA2, hA1); hB1 = MFMA(w, bB2, hB1);
    w = LD(5); hA0 = MFMA(w, bA3, hA0); hB0 = MFMA(w, bB3, hB0);
    w = LD(9); hA1 = MFMA(w, bA3, hA1); hB1 = MFMA(w, bB3, hB1);
    bA0 = packhalf(hA0, 0, true); bA1 = packhalf(hA0, 8, true);
    bA2 = packhalf(hA1, 0, true); bA3 = packhalf(hA1, 8, true);
    bB0 = packhalf(hB0, 0, true); bB1 = packhalf(hB0, 8, true);
    bB2 = packhalf(hB1, 0, true); bB3 = packhalf(hB1, 8, true);

    // sigma L2 (64->16, NO relu)
    floatx16 hsA, hsB;
    w = LD(10); hsA = MFMA(w, bA0, z);   hsB = MFMA(w, bB0, z);
    w = LD(11); hsA = MFMA(w, bA1, hsA); hsB = MFMA(w, bB1, hsB);
    w = LD(12); hsA = MFMA(w, bA2, hsA); hsB = MFMA(w, bB2, hsB);
    w = LD(13); hsA = MFMA(w, bA3, hsA); hsB = MFMA(w, bB3, hsB);
    const float sigmaA = hsA[0], sigmaB = hsB[0];
    const half8 bs2A = packhalf(hsA, 0, false);
    const half8 bs2B = packhalf(hsB, 0, false);

    // color L0 (19->64: s2 slots + views)
    w = LD(14); hA0 = MFMA(w, bs2A, z);    hB0 = MFMA(w, bs2B, z);
    w = LD(16); hA1 = MFMA(w, bs2A, z);    hB1 = MFMA(w, bs2B, z);
    w = LD(15); hA0 = MFMA(w, bvA.v, hA0); hB0 = MFMA(w, bvB.v, hB0);
    w = LD(17); hA1 = MFMA(w, bvA.v, hA1); hB1 = MFMA(w, bvB.v, hB1);
    bA0 = packhalf(hA0, 0, true); bA1 = packhalf(hA0, 8, true);
    bA2 = packhalf(hA1, 0, true); bA3 = packhalf(hA1, 8, true);
    bB0 = packhalf(hB0, 0, true); bB1 = packhalf(hB0, 8, true);
    bB2 = packhalf(hB1, 0, true); bB3 = packhalf(hB1, 8, true);

    // color L1
    w = LD(18); hA0 = MFMA(w, bA0, z);   hB0 = MFMA(w, bB0, z);
    w = LD(22); hA1 = MFMA(w, bA0, z);   hB1 = MFMA(w, bB0, z);
    w = LD(19); hA0 = MFMA(w, bA1, hA0); hB0 = MFMA(w, bB1, hB0);
    w = LD(23); hA1 = MFMA(w, bA1, hA1); hB1 = MFMA(w, bB1, hB1);
    w = LD(20); hA0 = MFMA(w, bA2, hA0); hB0 = MFMA(w, bB2, hB0);
    w = LD(24); hA1 = MFMA(w, bA2, hA1); hB1 = MFMA(w, bB2, hB1);
    w = LD(21); hA0 = MFMA(w, bA3, hA0); hB0 = MFMA(w, bB3, hB0);
    w = LD(25); hA1 = MFMA(w, bA3, hA1); hB1 = MFMA(w, bB3, hB1);
    bA0 = packhalf(hA0, 0, true); bA1 = packhalf(hA0, 8, true);
    bA2 = packhalf(hA1, 0, true); bA3 = packhalf(hA1, 8, true);
    bB0 = packhalf(hB0, 0, true); bB1 = packhalf(hB0, 8, true);
    bB2 = packhalf(hB1, 0, true); bB3 = packhalf(hB1, 8, true);

    // color L2
    w = LD(26); hA0 = MFMA(w, bA0, z);   hB0 = MFMA(w, bB0, z);
    w = LD(30); hA1 = MFMA(w, bA0, z);   hB1 = MFMA(w, bB0, z);
    w = LD(27); hA0 = MFMA(w, bA1, hA0); hB0 = MFMA(w, bB1, hB0);
    w = LD(31); hA1 = MFMA(w, bA1, hA1); hB1 = MFMA(w, bB1, hB1);
    w = LD(28); hA0 = MFMA(w, bA2, hA0); hB0 = MFMA(w, bB2, hB0);
    w = LD(32); hA1 = MFMA(w, bA2, hA1); hB1 = MFMA(w, bB2, hB1);
    w = LD(29); hA0 = MFMA(w, bA3, hA0); hB0 = MFMA(w, bB3, hB0);
    w = LD(33); hA1 = MFMA(w, bA3, hA1); hB1 = MFMA(w, bB3, hB1);
    bA0 = packhalf(hA0, 0, true); bA1 = packhalf(hA0, 8, true);
    bA2 = packhalf(hA1, 0, true); bA3 = packhalf(hA1, 8, true);
    bB0 = packhalf(hB0, 0, true); bB1 = packhalf(hB0, 8, true);
    bB2 = packhalf(hB1, 0, true); bB3 = packhalf(hB1, 8, true);

    // color L3 (64->3, NO relu)
    floatx16 hcA, hcB;
    w = LD(34); hcA = MFMA(w, bA0, z);   hcB = MFMA(w, bB0, z);
    w = LD(35); hcA = MFMA(w, bA1, hcA); hcB = MFMA(w, bB1, hcB);
    w = LD(36); hcA = MFMA(w, bA2, hcA); hcB = MFMA(w, bB2, hcB);
    w = LD(37); hcA = MFMA(w, bA3, hcA); hcB = MFMA(w, bB3, hcB);

    if (lane < 32) {
      float4 oA, oB;
      oA.x = hcA[0]; oA.y = hcA[1]; oA.z = hcA[2]; oA.w = sigmaA;
      oB.x = hcB[0]; oB.y = hcB[1]; oB.z = hcB[2]; oB.w = sigmaB;
      *(float4*)(out + (size_t)ptA * 4) = oA;
      *(float4*)(out + (size_t)ptB * 4) = oB;
    }
  }
#undef LD
}

extern "C" void kernel_launch(void* const* d_in, const int* in_sizes, int n_in,
                              void* d_out, int out_size, void* d_ws, size_t ws_size,
                              hipStream_t stream) {
  const float* x = (const float*)d_in[0];
  const float* sw0 = (const float*)d_in[1];
  const float* sw1 = (const float*)d_in[2];
  const float* sw2 = (const float*)d_in[3];
  const float* cw0 = (const float*)d_in[4];
  const float* cw1 = (const float*)d_in[5];
  const float* cw2 = (const float*)d_in[6];
  const float* cw3 = (const float*)d_in[7];
  float* out = (float*)d_out;

  const int npts = in_sizes[0] / 6;         // 1048576
  const int ntiles = npts >> 5;             // 32768
  const int blocks = (ntiles + 4 * TPW - 1) / (4 * TPW);  // 1024

  nerf_fused<<<blocks, 256, 0, stream>>>(x, sw0, sw1, sw2, cw0, cw1, cw2, cw3,
                                         out, npts);
}

// Round 11
// 112.450 us; speedup vs baseline: 5.7842x; 1.0379x over previous
//
#include <hip/hip_runtime.h>
#include <stdint.h>

typedef __attribute__((ext_vector_type(8))) _Float16 half8;
typedef __attribute__((ext_vector_type(2))) __fp16 fp16x2;
typedef __attribute__((ext_vector_type(16))) float floatx16;
typedef __attribute__((ext_vector_type(2))) short s16x2;
typedef unsigned int u32;
typedef unsigned short u16;

#define TPW 4  // tiles (of 32 points) per wave; processed 2 at a time

// f32 pair -> packed f16 (a->low16, b->high16), single v_cvt_pkrtz_f16_f32.
// Builtin returns __fp16-vector (NOT _Float16-vector) — union must match.
// NOTE R7: v_cvt_pk_bf16_f32 asm assembles on gfx950 but returns garbage.
// NOTE R8: inline-asm v_mfma_* corrupts results (no hazard nops) — intrinsics only.
__device__ __forceinline__ u32 pkf16(float a, float b) {
  union { fp16x2 v; u32 u; } c;
  c.v = __builtin_amdgcn_cvt_pkrtz(a, b);
  return c.u;
}

// relu on a packed f16 pair: signed-i16 max with 0. R5/R10-proven.
__device__ __forceinline__ u32 relu_pk(u32 t) {
  union { u32 u; s16x2 v; } c;
  c.u = t;
  s16x2 zz = {0, 0};
  c.v = __builtin_elementwise_max(c.v, zz);  // v_pk_max_i16
  return c.u;
}

// RNE f32->f16 for pool weights (bit-identical to R10)
__device__ __forceinline__ u16 rtnh(float a) {
  union { _Float16 h; u16 u; } c;
  c.h = (_Float16)a;
  return c.u;
}

// channel<->k-slot permutation (involution): swap bits 2 and 3 of low nibble.
// Maps C/D register order onto B-operand k-slots; baked into weight gather.
__device__ __forceinline__ int sigperm(int k) {
  int r = k & 15;
  int s = (r & 3) | ((r & 4) << 1) | ((r & 8) >> 1);
  return (k & ~15) | s;
}

// pack 8 consecutive accumulator regs (base=0 or 8) into one B-frag
__device__ __forceinline__ half8 packhalf(const floatx16 a, int base, bool relu) {
  union { u32 u[4]; half8 v; } r;
#pragma unroll
  for (int i = 0; i < 4; ++i) {
    u32 t = pkf16(a[base + 2 * i], a[base + 2 * i + 1]);
    r.u[i] = relu ? relu_pk(t) : t;
  }
  return r.v;
}

#define MFMA(A, B, C) __builtin_amdgcn_mfma_f32_32x32x16_f16(A, B, C, 0, 0, 0)

// Frag pool: 38 frags x 64 lanes x 16B = 38912 B. Frag ids:
//  0..1  s0[rt]          2..9  s1[rt*4+ks]    10..13 s2[ks]
// 14..17 c0[rt*2+ks]    18..25 c1[rt*4+ks]    26..33 c2[rt*4+ks]   34..37 c3[ks]
#define NFRAG 38

// ---- pre-kernel: build the fragment pool in global (d_ws), 1 frag/block ----
__global__ void build_pool(
    const float* __restrict__ w_s0, const float* __restrict__ w_s1,
    const float* __restrict__ w_s2, const float* __restrict__ w_c0,
    const float* __restrict__ w_c1, const float* __restrict__ w_c2,
    const float* __restrict__ w_c3, uint4* __restrict__ pool) {
  const int f = blockIdx.x;
  const int lane = threadIdx.x;      // 0..63
  const int m = lane & 31;
  const int kb = (lane >> 5) << 3;

  union { u16 e[8]; uint4 q; } u;
  if (f < 2) {                         // s0: 64x3, K padded to 16
    const int row = f * 32 + m;
#pragma unroll
    for (int j = 0; j < 8; ++j) {
      const int k = kb + j;
      u.e[j] = (k < 3) ? rtnh(w_s0[row * 3 + k]) : (u16)0;
    }
  } else if (f < 10) {                 // s1: 64x64
    const int g = f - 2, rt = g >> 2, ks = g & 3;
    const int row = rt * 32 + m;
#pragma unroll
    for (int j = 0; j < 8; ++j)
      u.e[j] = rtnh(w_s1[row * 64 + sigperm(ks * 16 + kb + j)]);
  } else if (f < 14) {                 // s2: 16x64 (rows 16..31 zero)
    const int ks = f - 10;
    const int row = (m < 16) ? m : 0;
#pragma unroll
    for (int j = 0; j < 8; ++j) {
      u16 v = rtnh(w_s2[row * 64 + sigperm(ks * 16 + kb + j)]);
      u.e[j] = (m < 16) ? v : (u16)0;
    }
  } else if (f < 18) {                 // c0: 64x18 (geo slots + view slots)
    const int g = f - 14, rt = g >> 1, ks = g & 1;
    const int row = rt * 32 + m;
#pragma unroll
    for (int j = 0; j < 8; ++j) {
      if (ks == 0) {
        const int c = sigperm(kb + j);   // s2-output channel in this k-slot
        u16 v = rtnh(w_c0[row * 18 + (c + 2)]);
        u.e[j] = (c == 0) ? (u16)0 : v;  // ch0 = sigma -> weight 0
      } else {
        const int kk = kb + j;           // views at k=0..2 of 2nd MFMA
        u16 v = rtnh(w_c0[row * 18 + kk]);
        u.e[j] = (kk < 3) ? v : (u16)0;
      }
    }
  } else if (f < 26) {                 // c1: 64x64
    const int g = f - 18, rt = g >> 2, ks = g & 3;
    const int row = rt * 32 + m;
#pragma unroll
    for (int j = 0; j < 8; ++j)
      u.e[j] = rtnh(w_c1[row * 64 + sigperm(ks * 16 + kb + j)]);
  } else if (f < 34) {                 // c2: 64x64
    const int g = f - 26, rt = g >> 2, ks = g & 3;
    const int row = rt * 32 + m;
#pragma unroll
    for (int j = 0; j < 8; ++j)
      u.e[j] = rtnh(w_c2[row * 64 + sigperm(ks * 16 + kb + j)]);
  } else {                             // c3: 3x64 (rows 3..31 zero)
    const int ks = f - 34;
    const int row = (m < 3) ? m : 0;
#pragma unroll
    for (int j = 0; j < 8; ++j) {
      u16 v = rtnh(w_c3[row * 64 + sigperm(ks * 16 + kb + j)]);
      u.e[j] = (m < 3) ? v : (u16)0;
    }
  }
  pool[f * 64 + lane] = u.q;
}

// NOTE: live set ~132 unified regs (68 arch + 64 MFMA acc). (256,3) is the
// max safe launch bound; (512,7) spilled catastrophically in R6 (650 us).
__global__ __launch_bounds__(256, 3) void nerf_fused(
    const float* __restrict__ x, const uint4* __restrict__ pool,
    float* __restrict__ out, int npts) {
  __shared__ __align__(16) u16 wl[NFRAG * 512];  // 38912 B

  // ---- prologue: coalesced pool -> LDS copy (L2-hot after first blocks) ----
  {
    uint4* lp = (uint4*)wl;
    for (int i = threadIdx.x; i < NFRAG * 64; i += 256) lp[i] = pool[i];
  }
  __syncthreads();

  const int lane = threadIdx.x & 63;
  const int wid = threadIdx.x >> 6;
  const int m = lane & 31;   // A-row / B-col (point) index within tile
  const int hi = lane >> 5;  // half-wave -> k-block

#define LD(F) (*(const half8*)(wl + (F) * 512 + lane * 8))

  // ---- main loop: 2 independent tiles (64 points) per iteration ----
  const int ntiles = npts >> 5;
  const int wgid = blockIdx.x * 4 + wid;
  const floatx16 z = (floatx16)0.0f;

  for (int t = 0; t < TPW; t += 2) {
    const int tileA = wgid * TPW + t;
    if (tileA >= ntiles) break;
    const int ptA = (tileA << 5) | m;
    const int ptB = ptA + 32;  // tileA is even & ntiles even -> tileB valid

    const float2* xpA = (const float2*)(x + (size_t)ptA * 6);
    const float2 a0 = xpA[0], a1 = xpA[1], a2 = xpA[2];
    const float2* xpB = (const float2*)(x + (size_t)ptB * 6);
    const float2 c0_ = xpB[0], c1_ = xpB[1], c2_ = xpB[2];

    union { u32 u[4]; half8 v; } bxA, bvA, bxB, bvB;
    bxA.u[0] = hi ? 0u : pkf16(a0.x, a0.y);   // (p0,p1) at k0,k1
    bxA.u[1] = hi ? 0u : pkf16(a1.x, 0.0f);   // (p2, 0)
    bxA.u[2] = 0u; bxA.u[3] = 0u;
    bvA.u[0] = hi ? 0u : pkf16(a1.y, a2.x);   // (v0,v1)
    bvA.u[1] = hi ? 0u : pkf16(a2.y, 0.0f);   // (v2, 0)
    bvA.u[2] = 0u; bvA.u[3] = 0u;
    bxB.u[0] = hi ? 0u : pkf16(c0_.x, c0_.y);
    bxB.u[1] = hi ? 0u : pkf16(c1_.x, 0.0f);
    bxB.u[2] = 0u; bxB.u[3] = 0u;
    bvB.u[0] = hi ? 0u : pkf16(c1_.y, c2_.x);
    bvB.u[1] = hi ? 0u : pkf16(c2_.y, 0.0f);
    bvB.u[2] = 0u; bvB.u[3] = 0u;

    floatx16 hA0, hA1, hB0, hB1;
    half8 w;

    // sigma L0 (K=3 padded)
    w = LD(0); hA0 = MFMA(w, bxA.v, z); hB0 = MFMA(w, bxB.v, z);
    w = LD(1); hA1 = MFMA(w, bxA.v, z); hB1 = MFMA(w, bxB.v, z);
    half8 bA0 = packhalf(hA0, 0, true), bA1 = packhalf(hA0, 8, true);
    half8 bA2 = packhalf(hA1, 0, true), bA3 = packhalf(hA1, 8, true);
    half8 bB0 = packhalf(hB0, 0, true), bB1 = packhalf(hB0, 8, true);
    half8 bB2 = packhalf(hB1, 0, true), bB3 = packhalf(hB1, 8, true);

    // sigma L1 (64->64)
    w = LD(2); hA0 = MFMA(w, bA0, z);   hB0 = MFMA(w, bB0, z);
    w = LD(6); hA1 = MFMA(w, bA0, z);   hB1 = MFMA(w, bB0, z);
    w = LD(3); hA0 = MFMA(w, bA1, hA0); hB0 = MFMA(w, bB1, hB0);
    w = LD(7); hA1 = MFMA(w, bA1, hA1); hB1 = MFMA(w, bB1, hB1);
    w = LD(4); hA0 = MFMA(w, bA2, hA0); hB0 = MFMA(w, bB2, hB0);
    w = LD(8); hA1 = MFMA(w, bA2, hA1); hB1 = MFMA(w, bB2, hB1);
    w = LD(5); hA0 = MFMA(w, bA3, hA0); hB0 = MFMA(w, bB3, hB0);
    w = LD(9); hA1 = MFMA(w, bA3, hA1); hB1 = MFMA(w, bB3, hB1);
    bA0 = packhalf(hA0, 0, true); bA1 = packhalf(hA0, 8, true);
    bA2 = packhalf(hA1, 0, true); bA3 = packhalf(hA1, 8, true);
    bB0 = packhalf(hB0, 0, true); bB1 = packhalf(hB0, 8, true);
    bB2 = packhalf(hB1, 0, true); bB3 = packhalf(hB1, 8, true);

    // sigma L2 (64->16, NO relu)
    floatx16 hsA, hsB;
    w = LD(10); hsA = MFMA(w, bA0, z);   hsB = MFMA(w, bB0, z);
    w = LD(11); hsA = MFMA(w, bA1, hsA); hsB = MFMA(w, bB1, hsB);
    w = LD(12); hsA = MFMA(w, bA2, hsA); hsB = MFMA(w, bB2, hsB);
    w = LD(13); hsA = MFMA(w, bA3, hsA); hsB = MFMA(w, bB3, hsB);
    const float sigmaA = hsA[0], sigmaB = hsB[0];
    const half8 bs2A = packhalf(hsA, 0, false);
    const half8 bs2B = packhalf(hsB, 0, false);

    // color L0 (19->64: s2 slots + views)
    w = LD(14); hA0 = MFMA(w, bs2A, z);    hB0 = MFMA(w, bs2B, z);
    w = LD(16); hA1 = MFMA(w, bs2A, z);    hB1 = MFMA(w, bs2B, z);
    w = LD(15); hA0 = MFMA(w, bvA.v, hA0); hB0 = MFMA(w, bvB.v, hB0);
    w = LD(17); hA1 = MFMA(w, bvA.v, hA1); hB1 = MFMA(w, bvB.v, hB1);
    bA0 = packhalf(hA0, 0, true); bA1 = packhalf(hA0, 8, true);
    bA2 = packhalf(hA1, 0, true); bA3 = packhalf(hA1, 8, true);
    bB0 = packhalf(hB0, 0, true); bB1 = packhalf(hB0, 8, true);
    bB2 = packhalf(hB1, 0, true); bB3 = packhalf(hB1, 8, true);

    // color L1
    w = LD(18); hA0 = MFMA(w, bA0, z);   hB0 = MFMA(w, bB0, z);
    w = LD(22); hA1 = MFMA(w, bA0, z);   hB1 = MFMA(w, bB0, z);
    w = LD(19); hA0 = MFMA(w, bA1, hA0); hB0 = MFMA(w, bB1, hB0);
    w = LD(23); hA1 = MFMA(w, bA1, hA1); hB1 = MFMA(w, bB1, hB1);
    w = LD(20); hA0 = MFMA(w, bA2, hA0); hB0 = MFMA(w, bB2, hB0);
    w = LD(24); hA1 = MFMA(w, bA2, hA1); hB1 = MFMA(w, bB2, hB1);
    w = LD(21); hA0 = MFMA(w, bA3, hA0); hB0 = MFMA(w, bB3, hB0);
    w = LD(25); hA1 = MFMA(w, bA3, hA1); hB1 = MFMA(w, bB3, hB1);
    bA0 = packhalf(hA0, 0, true); bA1 = packhalf(hA0, 8, true);
    bA2 = packhalf(hA1, 0, true); bA3 = packhalf(hA1, 8, true);
    bB0 = packhalf(hB0, 0, true); bB1 = packhalf(hB0, 8, true);
    bB2 = packhalf(hB1, 0, true); bB3 = packhalf(hB1, 8, true);

    // color L2
    w = LD(26); hA0 = MFMA(w, bA0, z);   hB0 = MFMA(w, bB0, z);
    w = LD(30); hA1 = MFMA(w, bA0, z);   hB1 = MFMA(w, bB0, z);
    w = LD(27); hA0 = MFMA(w, bA1, hA0); hB0 = MFMA(w, bB1, hB0);
    w = LD(31); hA1 = MFMA(w, bA1, hA1); hB1 = MFMA(w, bB1, hB1);
    w = LD(28); hA0 = MFMA(w, bA2, hA0); hB0 = MFMA(w, bB2, hB0);
    w = LD(32); hA1 = MFMA(w, bA2, hA1); hB1 = MFMA(w, bB2, hB1);
    w = LD(29); hA0 = MFMA(w, bA3, hA0); hB0 = MFMA(w, bB3, hB0);
    w = LD(33); hA1 = MFMA(w, bA3, hA1); hB1 = MFMA(w, bB3, hB1);
    bA0 = packhalf(hA0, 0, true); bA1 = packhalf(hA0, 8, true);
    bA2 = packhalf(hA1, 0, true); bA3 = packhalf(hA1, 8, true);
    bB0 = packhalf(hB0, 0, true); bB1 = packhalf(hB0, 8, true);
    bB2 = packhalf(hB1, 0, true); bB3 = packhalf(hB1, 8, true);

    // color L3 (64->3, NO relu)
    floatx16 hcA, hcB;
    w = LD(34); hcA = MFMA(w, bA0, z);   hcB = MFMA(w, bB0, z);
    w = LD(35); hcA = MFMA(w, bA1, hcA); hcB = MFMA(w, bB1, hcB);
    w = LD(36); hcA = MFMA(w, bA2, hcA); hcB = MFMA(w, bB2, hcB);
    w = LD(37); hcA = MFMA(w, bA3, hcA); hcB = MFMA(w, bB3, hcB);

    if (lane < 32) {
      float4 oA, oB;
      oA.x = hcA[0]; oA.y = hcA[1]; oA.z = hcA[2]; oA.w = sigmaA;
      oB.x = hcB[0]; oB.y = hcB[1]; oB.z = hcB[2]; oB.w = sigmaB;
      *(float4*)(out + (size_t)ptA * 4) = oA;
      *(float4*)(out + (size_t)ptB * 4) = oB;
    }
  }
#undef LD
}

extern "C" void kernel_launch(void* const* d_in, const int* in_sizes, int n_in,
                              void* d_out, int out_size, void* d_ws, size_t ws_size,
                              hipStream_t stream) {
  const float* x = (const float*)d_in[0];
  const float* sw0 = (const float*)d_in[1];
  const float* sw1 = (const float*)d_in[2];
  const float* sw2 = (const float*)d_in[3];
  const float* cw0 = (const float*)d_in[4];
  const float* cw1 = (const float*)d_in[5];
  const float* cw2 = (const float*)d_in[6];
  const float* cw3 = (const float*)d_in[7];
  float* out = (float*)d_out;
  uint4* pool = (uint4*)d_ws;  // 38912 B used

  const int npts = in_sizes[0] / 6;         // 1048576
  const int ntiles = npts >> 5;             // 32768
  const int blocks = (ntiles + 4 * TPW - 1) / (4 * TPW);  // 2048

  build_pool<<<NFRAG, 64, 0, stream>>>(sw0, sw1, sw2, cw0, cw1, cw2, cw3, pool);
  nerf_fused<<<blocks, 256, 0, stream>>>(x, pool, out, npts);
}